// Round 9
// baseline (113.190 us; speedup 1.0000x reference)
//
#include <hip/hip_runtime.h>
#include <hip/hip_bf16.h>
#include <type_traits>

#define AS1 __attribute__((address_space(1)))
#define AS3 __attribute__((address_space(3)))

typedef __attribute__((ext_vector_type(4))) float f32x4;
typedef __attribute__((ext_vector_type(8))) short bf16x8;

template <int V> using ic = std::integral_constant<int, V>;

static constexpr int B_   = 2048;
static constexpr int IN_  = 1024;
static constexpr int HID_ = 2048;
static constexpr int NB_  = 8;
static constexpr int BS_  = 256;   // block size
static constexpr int G3_  = 768;   // 3*BS_

// packed fp32x2 -> bf16x2 RNE, single VALU op (no builtin on gfx950)
__device__ __forceinline__ unsigned cvtpk(float lo, float hi) {
  unsigned r;
  asm("v_cvt_pk_bf16_f32 %0, %1, %2" : "=v"(r) : "v"(lo), "v"(hi));
  return r;
}

__device__ __forceinline__ unsigned short f2bf(float f) {
  unsigned u = __builtin_bit_cast(unsigned, f);
  u = (u + 0x7FFFu + ((u >> 16) & 1u)) >> 16;
  return (unsigned short)u;
}

// Convert ONLY the weights to bf16 (x and h are consumed fp32 by the GEMM).
__global__ void cvt_w(const float* __restrict__ Wih, const float* __restrict__ Whh,
                      unsigned short* __restrict__ dst) {
  constexpr int c0 = (NB_ * G3_ * IN_) / 4;   // 1572864 float4s of Wih
  constexpr int n4 = c0 + (NB_ * G3_ * BS_) / 4;
  int i = blockIdx.x * blockDim.x + threadIdx.x;
  int stride = gridDim.x * blockDim.x;
  for (; i < n4; i += stride) {
    float4 v = (i < c0) ? reinterpret_cast<const float4*>(Wih)[i]
                        : reinterpret_cast<const float4*>(Whh)[i - c0];
    ushort4 o;
    o.x = f2bf(v.x); o.y = f2bf(v.y); o.z = f2bf(v.z); o.w = f2bf(v.w);
    reinterpret_cast<ushort4*>(dst)[i] = o;
  }
}

// ---------- fused block-GRU MFMA kernel: A direct-from-global, W via LDS ----------
// Tile: 128 batch rows x 64 out-cols (192 gate cols); 4 waves (2x2), wave 64x32.
// Accumulators: [0]=r (K=1280 combined), [1]=z (combined), [2]=i_n, [3]=h_n.
// A-fragments: loaded DIRECT from fp32 x/h with the MFMA lane pattern
// (row=base+(lane&15), k=(lane>>4)*8, 16B/lane -> each 128B L2 line fully used
// across a step's 8 frags), converted in-reg via v_cvt_pk_bf16_f32. A never
// touches LDS: LDS traffic/block-step 120->72 KB, and NO cvt pass for x/h.
// W: bf16 (pre-converted ws), global_load_lds into 2x24KB double buffer,
// XOR-swizzled (phys = logical ^ ((row&7)<<4), source pre-swizzled, rule #21).
// Issue order A0,A1,W per step => compiler waits cvt1 at vmcnt(6) (W in flight);
// barrier auto-drain only catches W's tail after ~48 MFMAs of gap.
__global__ __launch_bounds__(256, 2) void gru_mfma(
    const float* __restrict__ xf,              // [2048][1024] fp32
    const float* __restrict__ hf,              // [2048][2048] fp32
    const unsigned short* __restrict__ wihb,   // [8][768][1024] bf16
    const unsigned short* __restrict__ whhb,   // [8][768][256] bf16
    const float* __restrict__ b_ih,            // [8][768]
    const float* __restrict__ b_hh,            // [8][768]
    float* __restrict__ out)                   // [2048][2048]
{
  __shared__ __align__(16) char lds[2][24576];   // W only: [192][64] bf16 per buf

  const int t    = threadIdx.x;
  const int lane = t & 63;
  const int wid  = t >> 6;
  const int wm   = wid >> 1;     // wave row (0..1) -> 64-row half
  const int wn   = wid & 1;      // wave col (0..1) -> 32-col half

  // Bijective XCD swizzle: nwg=512 = 8 XCDs x 64 -> each XCD owns one GRU block n
  // (its bf16 W panel = 1.9 MB, L2-resident per XCD).
  const int bid = blockIdx.x;
  const int swz = (bid & 7) * 64 + (bid >> 3);
  const int mrow0 = (swz & 15) * 128;
  const int ct    = swz >> 4;
  const int n     = ct >> 2;          // GRU block index
  const int s0    = (ct & 3) * 64;    // col offset within block

  // W staging pass q writes phys LDS offset op = q*4096 + t*16; the element that
  // belongs there is logical ol = op ^ (((op>>7)&7)<<4) (involution on bits [6:4]).
  int wgrow[6], wcb[6];
#pragma unroll
  for (int q = 0; q < 6; ++q) {
    int op = q * 4096 + t * 16;
    int ol = op ^ (((op >> 7) & 7) << 4);
    int wr = ol >> 7;             // 0..191
    wgrow[q] = n * G3_ + (wr >> 6) * BS_ + s0 + (wr & 63);  // global W row
    wcb[q]   = ol & 127;          // byte offset within 128B row
  }

  f32x4 acc[4][4][2] = {};   // [set][mi][ni]

  auto stageW = [&](int buf, int t2) {
    const bool ph1 = t2 < 16;
    const int ks = ph1 ? t2 : (t2 - 16);
    char* base = (char*)lds[buf];
#pragma unroll
    for (int q = 0; q < 6; ++q) {
      const char* src = ph1
        ? (const char*)wihb + ((size_t)wgrow[q] * IN_ + ks * 64) * 2 + wcb[q]
        : (const char*)whhb + ((size_t)wgrow[q] * BS_ + ks * 64) * 2 + wcb[q];
      __builtin_amdgcn_global_load_lds((const AS1 void*)src,
                                       (AS3 void*)(base + q * 4096 + wid * 1024), 16, 0, 0);
    }
  };

  // A direct gather: frag mi covers rows [mrow0+wm*64+mi*16, +16), k window of 32.
  auto issueA = [&](int tt, int ksub, float4 (&tmp)[4][2]) {
#pragma unroll
    for (int mi = 0; mi < 4; ++mi) {
      int row = mrow0 + wm * 64 + mi * 16 + (lane & 15);
      int kk  = ksub * 32 + (lane >> 4) * 8;
      const float* src = (tt < 16)
        ? xf + (size_t)row * IN_  + tt * 64 + kk
        : hf + (size_t)row * HID_ + n * BS_ + (tt - 16) * 64 + kk;
      tmp[mi][0] = *reinterpret_cast<const float4*>(src);
      tmp[mi][1] = *reinterpret_cast<const float4*>(src + 4);
    }
  };
  auto pack8 = [&](const float4& a, const float4& b) {
    union { unsigned u[4]; bf16x8 v; } r;
    r.u[0] = cvtpk(a.x, a.y); r.u[1] = cvtpk(a.z, a.w);
    r.u[2] = cvtpk(b.x, b.y); r.u[3] = cvtpk(b.z, b.w);
    return r.v;
  };
  auto cvtA = [&](float4 (&tmp)[4][2], bf16x8 (&af)[4]) {
#pragma unroll
    for (int mi = 0; mi < 4; ++mi) af[mi] = pack8(tmp[mi][0], tmp[mi][1]);
  };

  auto loadWg = [&](const char* buf, int g, int ksub, bf16x8 (&wf)[2]) {
#pragma unroll
    for (int ni = 0; ni < 2; ++ni) {
      int wr  = g * 64 + wn * 32 + ni * 16 + (lane & 15);
      int off = wr * 128 + ksub * 64 + ((lane >> 4) * 16);
      off ^= (wr & 7) << 4;
      wf[ni] = *reinterpret_cast<const bf16x8*>(buf + off);
    }
  };
  auto mfmaG = [&](auto setc, bf16x8 (&af)[4], bf16x8 (&wf)[2]) {
    constexpr int set = decltype(setc)::value;
    __builtin_amdgcn_s_setprio(1);
#pragma unroll
    for (int mi = 0; mi < 4; ++mi)
#pragma unroll
      for (int ni = 0; ni < 2; ++ni)
        acc[set][mi][ni] = __builtin_amdgcn_mfma_f32_16x16x32_bf16(
            af[mi], wf[ni], acc[set][mi][ni], 0, 0, 0);
    __builtin_amdgcn_s_setprio(0);
  };

  // ---- prologue: stage W tile 0 ----
  stageW(0, 0);
  __syncthreads();   // auto-drain: W(0) landed

  // ---- 20 K-steps (16 input + 4 hidden), fully unrolled, W double-buffered ----
#pragma unroll
  for (int tt = 0; tt < 20; ++tt) {
    const char* cur = (const char*)lds[tt & 1];
    const int oth = (tt & 1) ^ 1;
    float4 t0[4][2], t1[4][2];
    bf16x8 af[4], wf[2];

    issueA(tt, 0, t0);                    // oldest in flight
    issueA(tt, 1, t1);
    if (tt < 19) stageW(oth, tt + 1);     // newest: cvt waits leave W in flight
    __builtin_amdgcn_sched_barrier(0);

    // ksub 0
    cvtA(t0, af);
    loadWg(cur, 0, 0, wf); mfmaG(ic<0>{}, af, wf);
    loadWg(cur, 1, 0, wf); mfmaG(ic<1>{}, af, wf);
    loadWg(cur, 2, 0, wf);
    if (tt < 16) mfmaG(ic<2>{}, af, wf); else mfmaG(ic<3>{}, af, wf);
    // ksub 1
    cvtA(t1, af);
    loadWg(cur, 0, 1, wf); mfmaG(ic<0>{}, af, wf);
    loadWg(cur, 1, 1, wf); mfmaG(ic<1>{}, af, wf);
    loadWg(cur, 2, 1, wf);
    if (tt < 16) mfmaG(ic<2>{}, af, wf); else mfmaG(ic<3>{}, af, wf);

    __syncthreads();   // all waves done reading cur; W(t+1) landed (drain)
  }

  // ---- epilogue: gates + output ----
#pragma unroll
  for (int ni = 0; ni < 2; ++ni) {
    int scol = s0 + wn * 32 + ni * 16 + (lane & 15);
    float br_i = b_ih[n * G3_ + 0 * BS_ + scol];
    float bz_i = b_ih[n * G3_ + 1 * BS_ + scol];
    float bn_i = b_ih[n * G3_ + 2 * BS_ + scol];
    float br_h = b_hh[n * G3_ + 0 * BS_ + scol];
    float bz_h = b_hh[n * G3_ + 1 * BS_ + scol];
    float bn_h = b_hh[n * G3_ + 2 * BS_ + scol];
    int gcol = n * BS_ + scol;
#pragma unroll
    for (int mi = 0; mi < 4; ++mi) {
#pragma unroll
      for (int i = 0; i < 4; ++i) {
        int row = mrow0 + wm * 64 + mi * 16 + (lane >> 4) * 4 + i;  // C/D: col=lane&15, row=(lane>>4)*4+reg
        float hprev = hf[(size_t)row * HID_ + gcol];
        float rr = acc[0][mi][ni][i] + br_i + br_h;
        float zz = acc[1][mi][ni][i] + bz_i + bz_h;
        float r  = 1.f / (1.f + __expf(-rr));
        float z  = 1.f / (1.f + __expf(-zz));
        float ng = tanhf(acc[2][mi][ni][i] + bn_i + r * (acc[3][mi][ni][i] + bn_h));
        out[(size_t)row * HID_ + gcol] = (1.f - z) * ng + z * hprev;
      }
    }
  }
}

// ---------- fallback (only if ws too small): naive fp32 ----------
__global__ void gru_naive(const float* __restrict__ x, const float* __restrict__ h,
                          const float* __restrict__ Wih, const float* __restrict__ Whh,
                          const float* __restrict__ bih, const float* __restrict__ bhh,
                          float* __restrict__ out) {
  int b = blockIdx.x;
  int n = blockIdx.y;
  int s = threadIdx.x;   // 256
  __shared__ float xs[1024];
  __shared__ float hs[256];
  for (int i = threadIdx.x; i < 1024; i += 256) xs[i] = x[(size_t)b * IN_ + i];
  if (threadIdx.x < 256) hs[threadIdx.x] = h[(size_t)b * HID_ + n * BS_ + threadIdx.x];
  __syncthreads();
  float gi[3], gh[3];
  for (int g = 0; g < 3; ++g) {
    const float* w = Wih + ((size_t)(n * G3_ + g * BS_ + s)) * IN_;
    float a = 0.f;
    for (int k = 0; k < IN_; ++k) a += xs[k] * w[k];
    gi[g] = a + bih[n * G3_ + g * BS_ + s];
    const float* w2 = Whh + ((size_t)(n * G3_ + g * BS_ + s)) * BS_;
    float a2 = 0.f;
    for (int k = 0; k < BS_; ++k) a2 += hs[k] * w2[k];
    gh[g] = a2 + bhh[n * G3_ + g * BS_ + s];
  }
  float r = 1.f / (1.f + expf(-(gi[0] + gh[0])));
  float z = 1.f / (1.f + expf(-(gi[1] + gh[1])));
  float ng = tanhf(gi[2] + r * gh[2]);
  out[(size_t)b * HID_ + n * BS_ + s] = (1.f - z) * ng + z * hs[s];
}

extern "C" void kernel_launch(void* const* d_in, const int* in_sizes, int n_in,
                              void* d_out, int out_size, void* d_ws, size_t ws_size,
                              hipStream_t stream) {
  const float* x   = (const float*)d_in[0];
  const float* h   = (const float*)d_in[1];
  const float* Wih = (const float*)d_in[2];
  const float* Whh = (const float*)d_in[3];
  const float* bih = (const float*)d_in[4];
  const float* bhh = (const float*)d_in[5];
  float* out = (float*)d_out;

  const size_t szwih = (size_t)NB_ * G3_ * IN_;
  const size_t szwhh = (size_t)NB_ * G3_ * BS_;
  const size_t need  = (szwih + szwhh) * 2;

  if (ws_size >= need) {
    unsigned short* wihb = (unsigned short*)d_ws;
    unsigned short* whhb = wihb + szwih;
    cvt_w<<<1024, 256, 0, stream>>>(Wih, Whh, wihb);
    gru_mfma<<<512, 256, 0, stream>>>(x, h, wihb, whhb, bih, bhh, out);
  } else {
    dim3 grid(B_, NB_);
    gru_naive<<<grid, 256, 0, stream>>>(x, h, Wih, Whh, bih, bhh, out);
  }
}

// Round 10
// 56.061 us; speedup vs baseline: 2.0191x; 2.0191x over previous
//
#include <hip/hip_runtime.h>
#include <hip/hip_bf16.h>
#include <type_traits>

#define AS1 __attribute__((address_space(1)))
#define AS3 __attribute__((address_space(3)))

typedef __attribute__((ext_vector_type(4))) float f32x4;
typedef __attribute__((ext_vector_type(8))) short bf16x8;

template <int V> using ic = std::integral_constant<int, V>;

static constexpr int B_   = 2048;
static constexpr int IN_  = 1024;
static constexpr int HID_ = 2048;
static constexpr int NB_  = 8;
static constexpr int BS_  = 256;   // block size
static constexpr int G3_  = 768;   // 3*BS_

// packed fp32x2 -> bf16x2 RNE, single VALU op (no builtin on gfx950)
__device__ __forceinline__ unsigned cvtpk(float lo, float hi) {
  unsigned r;
  asm("v_cvt_pk_bf16_f32 %0, %1, %2" : "=v"(r) : "v"(lo), "v"(hi));
  return r;
}

__device__ __forceinline__ unsigned short f2bf(float f) {
  unsigned u = __builtin_bit_cast(unsigned, f);
  u = (u + 0x7FFFu + ((u >> 16) & 1u)) >> 16;
  return (unsigned short)u;
}

// Convert ONLY the weights to bf16 (x and h are converted inside the GEMM's
// A-staging path -> cvt traffic 77 MB -> 40 MB).
__global__ void cvt_w(const float* __restrict__ Wih, const float* __restrict__ Whh,
                      unsigned short* __restrict__ dst) {
  constexpr int c0 = (NB_ * G3_ * IN_) / 4;
  constexpr int n4 = c0 + (NB_ * G3_ * BS_) / 4;
  int i = blockIdx.x * blockDim.x + threadIdx.x;
  int stride = gridDim.x * blockDim.x;
  for (; i < n4; i += stride) {
    float4 v = (i < c0) ? reinterpret_cast<const float4*>(Wih)[i]
                        : reinterpret_cast<const float4*>(Whh)[i - c0];
    ushort4 o;
    o.x = f2bf(v.x); o.y = f2bf(v.y); o.z = f2bf(v.z); o.w = f2bf(v.w);
    reinterpret_cast<ushort4*>(dst)[i] = o;
  }
}

// ---------- fused block-GRU MFMA kernel: hybrid staging ----------
// Tile: 128 batch rows x 64 out-cols (192 gate cols); 4 waves (2x2), wave 64x32.
// Accumulators: [0]=r (K=1280 combined), [1]=z (combined), [2]=i_n, [3]=h_n.
// LDS: 2 buffers x 40KB { A [128][64]bf16 @0, W [192][64]bf16 @16384 },
// XOR-swizzled phys = logical ^ ((row&7)<<4).
// W: global_load_lds from bf16 ws (source pre-swizzled, rule #21) - no VGPR cost.
// A: reg-staged from fp32 x/h in STAGING layout (coalesced - round-9 lesson:
// never gather global in MFMA frag layout) -> v_cvt_pk_bf16_f32 -> ds_write_b128,
// issued at step top / written after compute (T14). A loads issued BEFORE W so
// the compiler's auto-wait before the cvt leaves the 6 W loads in flight.
__global__ __launch_bounds__(256, 2) void gru_mfma(
    const float* __restrict__ xf,              // [2048][1024] fp32
    const float* __restrict__ hf,              // [2048][2048] fp32
    const unsigned short* __restrict__ wihb,   // [8][768][1024] bf16
    const unsigned short* __restrict__ whhb,   // [8][768][256] bf16
    const float* __restrict__ b_ih,            // [8][768]
    const float* __restrict__ b_hh,            // [8][768]
    float* __restrict__ out)                   // [2048][2048]
{
  __shared__ __align__(16) char lds[2][40960];   // per buf: A @0 (16KB), W @16384 (24KB)

  const int t    = threadIdx.x;
  const int lane = t & 63;
  const int wid  = t >> 6;
  const int wm   = wid >> 1;     // wave row (0..1) -> 64-row half
  const int wn   = wid & 1;      // wave col (0..1) -> 32-col half

  // Bijective XCD swizzle: nwg=512 = 8 XCDs x 64 -> each XCD owns one GRU block n
  // (its bf16 W panel = 1.9 MB, L2-resident per XCD).
  const int bid = blockIdx.x;
  const int swz = (bid & 7) * 64 + (bid >> 3);
  const int mrow0 = (swz & 15) * 128;
  const int ct    = swz >> 4;
  const int n     = ct >> 2;          // GRU block index
  const int s0    = (ct & 3) * 64;    // col offset within block

  // Staging pass p targets phys LDS offset op = p*4096 + t*16 (region-local);
  // the element that belongs there is logical ol = op ^ (((op>>7)&7)<<4)
  // (involution on byte bits [6:4]; row bits untouched).
  int arow[4], acolE[4];
#pragma unroll
  for (int p = 0; p < 4; ++p) {
    int op = p * 4096 + t * 16;
    int ol = op ^ (((op >> 7) & 7) << 4);
    arow[p]  = ol >> 7;           // 0..127
    acolE[p] = (ol & 127) >> 1;   // element offset (multiple of 8)
  }
  int wgrow[6], wcb[6];
#pragma unroll
  for (int q = 0; q < 6; ++q) {
    int op = q * 4096 + t * 16;
    int ol = op ^ (((op >> 7) & 7) << 4);
    int wr = ol >> 7;             // 0..191
    wgrow[q] = n * G3_ + (wr >> 6) * BS_ + s0 + (wr & 63);  // global W row
    wcb[q]   = ol & 127;          // byte offset within 128B row
  }

  f32x4 acc[4][4][2] = {};   // [set][mi][ni]
  float4 sa[4][2];           // A staging regs (32 VGPR)

  auto issueA = [&](int t2) {            // coalesced: staging layout, fp32
#pragma unroll
    for (int p = 0; p < 4; ++p) {
      const float* src = (t2 < 16)
        ? xf + (size_t)(mrow0 + arow[p]) * IN_  + t2 * 64 + acolE[p]
        : hf + (size_t)(mrow0 + arow[p]) * HID_ + n * BS_ + (t2 - 16) * 64 + acolE[p];
      sa[p][0] = *reinterpret_cast<const float4*>(src);
      sa[p][1] = *reinterpret_cast<const float4*>(src + 4);
    }
  };
  auto stageW = [&](int buf, int t2) {   // 6x global_load_lds, 16B
    const bool ph1 = t2 < 16;
    const int ks = ph1 ? t2 : (t2 - 16);
    char* base = (char*)lds[buf] + 16384;
#pragma unroll
    for (int q = 0; q < 6; ++q) {
      const char* src = ph1
        ? (const char*)wihb + ((size_t)wgrow[q] * IN_ + ks * 64) * 2 + wcb[q]
        : (const char*)whhb + ((size_t)wgrow[q] * BS_ + ks * 64) * 2 + wcb[q];
      __builtin_amdgcn_global_load_lds((const AS1 void*)src,
                                       (AS3 void*)(base + q * 4096 + wid * 1024), 16, 0, 0);
    }
  };
  auto pack8 = [&](const float4& a, const float4& b) {
    union { unsigned u[4]; bf16x8 v; } r;
    r.u[0] = cvtpk(a.x, a.y); r.u[1] = cvtpk(a.z, a.w);
    r.u[2] = cvtpk(b.x, b.y); r.u[3] = cvtpk(b.z, b.w);
    return r.v;
  };
  auto writeA = [&](int buf) {           // cvt + ds_write (linear phys offset)
    char* base = (char*)lds[buf];
#pragma unroll
    for (int p = 0; p < 4; ++p)
      *reinterpret_cast<bf16x8*>(base + p * 4096 + t * 16) = pack8(sa[p][0], sa[p][1]);
  };

  auto loadA = [&](const char* buf, bf16x8 (&af)[2][4]) {
#pragma unroll
    for (int ksub = 0; ksub < 2; ++ksub)
#pragma unroll
      for (int mi = 0; mi < 4; ++mi) {
        int ar  = wm * 64 + mi * 16 + (lane & 15);
        int off = ar * 128 + ksub * 64 + ((lane >> 4) * 16);
        off ^= (ar & 7) << 4;
        af[ksub][mi] = *reinterpret_cast<const bf16x8*>(buf + off);
      }
  };
  auto loadW = [&](const char* buf, int g, bf16x8 (&wf)[2][2]) {
#pragma unroll
    for (int ksub = 0; ksub < 2; ++ksub)
#pragma unroll
      for (int ni = 0; ni < 2; ++ni) {
        int wr  = g * 64 + wn * 32 + ni * 16 + (lane & 15);
        int off = wr * 128 + ksub * 64 + ((lane >> 4) * 16);
        off ^= (wr & 7) << 4;
        wf[ksub][ni] = *reinterpret_cast<const bf16x8*>(buf + 16384 + off);
      }
  };
  auto mfmaSet = [&](auto setc, bf16x8 (&af)[2][4], bf16x8 (&wf)[2][2]) {
    constexpr int set = decltype(setc)::value;
    __builtin_amdgcn_s_setprio(1);
#pragma unroll
    for (int ksub = 0; ksub < 2; ++ksub)
#pragma unroll
      for (int mi = 0; mi < 4; ++mi)
#pragma unroll
        for (int ni = 0; ni < 2; ++ni)
          acc[set][mi][ni] = __builtin_amdgcn_mfma_f32_16x16x32_bf16(
              af[ksub][mi], wf[ksub][ni], acc[set][mi][ni], 0, 0, 0);
    __builtin_amdgcn_s_setprio(0);
  };

  // ---- prologue: stage tile 0 into buf0 ----
  issueA(0);
  stageW(0, 0);
  writeA(0);           // compiler waits A loads (vmcnt(6): W stays in flight)
  __syncthreads();     // drains W(0) + ds_writes

  // ---- 20 K-steps (16 input + 4 hidden), fully unrolled, dbuf, 1 barrier ----
#pragma unroll
  for (int tt = 0; tt < 20; ++tt) {
    const char* cur = (const char*)lds[tt & 1];
    const int oth = (tt & 1) ^ 1;
    bf16x8 af[2][4], wf[2][2];

    if (tt < 19) { issueA(tt + 1); stageW(oth, tt + 1); }   // issue early
    __builtin_amdgcn_sched_barrier(0);                      // pin issues above compute

    loadA(cur, af);
    loadW(cur, 0, wf); mfmaSet(ic<0>{}, af, wf);
    loadW(cur, 1, wf); mfmaSet(ic<1>{}, af, wf);
    loadW(cur, 2, wf);
    if (tt < 16) mfmaSet(ic<2>{}, af, wf);
    else         mfmaSet(ic<3>{}, af, wf);

    __builtin_amdgcn_sched_barrier(0);                      // write-late boundary
    if (tt < 19) writeA(oth);   // auto vmcnt leaves W in flight (A issued first)
    __syncthreads();            // drain: W(t+1) landed, A writes visible
  }

  // ---- epilogue: gates + output ----
#pragma unroll
  for (int ni = 0; ni < 2; ++ni) {
    int scol = s0 + wn * 32 + ni * 16 + (lane & 15);
    float br_i = b_ih[n * G3_ + 0 * BS_ + scol];
    float bz_i = b_ih[n * G3_ + 1 * BS_ + scol];
    float bn_i = b_ih[n * G3_ + 2 * BS_ + scol];
    float br_h = b_hh[n * G3_ + 0 * BS_ + scol];
    float bz_h = b_hh[n * G3_ + 1 * BS_ + scol];
    float bn_h = b_hh[n * G3_ + 2 * BS_ + scol];
    int gcol = n * BS_ + scol;
#pragma unroll
    for (int mi = 0; mi < 4; ++mi) {
#pragma unroll
      for (int i = 0; i < 4; ++i) {
        int row = mrow0 + wm * 64 + mi * 16 + (lane >> 4) * 4 + i;  // C/D: col=lane&15, row=(lane>>4)*4+reg
        float hprev = hf[(size_t)row * HID_ + gcol];
        float rr = acc[0][mi][ni][i] + br_i + br_h;
        float zz = acc[1][mi][ni][i] + bz_i + bz_h;
        float r  = 1.f / (1.f + __expf(-rr));
        float z  = 1.f / (1.f + __expf(-zz));
        float ng = tanhf(acc[2][mi][ni][i] + bn_i + r * (acc[3][mi][ni][i] + bn_h));
        out[(size_t)row * HID_ + gcol] = (1.f - z) * ng + z * hprev;
      }
    }
  }
}

// ---------- fallback (only if ws too small): naive fp32 ----------
__global__ void gru_naive(const float* __restrict__ x, const float* __restrict__ h,
                          const float* __restrict__ Wih, const float* __restrict__ Whh,
                          const float* __restrict__ bih, const float* __restrict__ bhh,
                          float* __restrict__ out) {
  int b = blockIdx.x;
  int n = blockIdx.y;
  int s = threadIdx.x;   // 256
  __shared__ float xs[1024];
  __shared__ float hs[256];
  for (int i = threadIdx.x; i < 1024; i += 256) xs[i] = x[(size_t)b * IN_ + i];
  if (threadIdx.x < 256) hs[threadIdx.x] = h[(size_t)b * HID_ + n * BS_ + threadIdx.x];
  __syncthreads();
  float gi[3], gh[3];
  for (int g = 0; g < 3; ++g) {
    const float* w = Wih + ((size_t)(n * G3_ + g * BS_ + s)) * IN_;
    float a = 0.f;
    for (int k = 0; k < IN_; ++k) a += xs[k] * w[k];
    gi[g] = a + bih[n * G3_ + g * BS_ + s];
    const float* w2 = Whh + ((size_t)(n * G3_ + g * BS_ + s)) * BS_;
    float a2 = 0.f;
    for (int k = 0; k < BS_; ++k) a2 += hs[k] * w2[k];
    gh[g] = a2 + bhh[n * G3_ + g * BS_ + s];
  }
  float r = 1.f / (1.f + expf(-(gi[0] + gh[0])));
  float z = 1.f / (1.f + expf(-(gi[1] + gh[1])));
  float ng = tanhf(gi[2] + r * gh[2]);
  out[(size_t)b * HID_ + n * BS_ + s] = (1.f - z) * ng + z * hs[s];
}

extern "C" void kernel_launch(void* const* d_in, const int* in_sizes, int n_in,
                              void* d_out, int out_size, void* d_ws, size_t ws_size,
                              hipStream_t stream) {
  const float* x   = (const float*)d_in[0];
  const float* h   = (const float*)d_in[1];
  const float* Wih = (const float*)d_in[2];
  const float* Whh = (const float*)d_in[3];
  const float* bih = (const float*)d_in[4];
  const float* bhh = (const float*)d_in[5];
  float* out = (float*)d_out;

  const size_t szwih = (size_t)NB_ * G3_ * IN_;
  const size_t szwhh = (size_t)NB_ * G3_ * BS_;
  const size_t need  = (szwih + szwhh) * 2;

  if (ws_size >= need) {
    unsigned short* wihb = (unsigned short*)d_ws;
    unsigned short* whhb = wihb + szwih;
    cvt_w<<<1024, 256, 0, stream>>>(Wih, Whh, wihb);
    gru_mfma<<<512, 256, 0, stream>>>(x, h, wihb, whhb, bih, bhh, out);
  } else {
    dim3 grid(B_, NB_);
    gru_naive<<<grid, 256, 0, stream>>>(x, h, Wih, Whh, bih, bhh, out);
  }
}

// Round 11
// 55.630 us; speedup vs baseline: 2.0347x; 1.0077x over previous
//
#include <hip/hip_runtime.h>
#include <hip/hip_bf16.h>
#include <type_traits>

#define AS1 __attribute__((address_space(1)))
#define AS3 __attribute__((address_space(3)))

typedef __attribute__((ext_vector_type(4))) float f32x4;
typedef __attribute__((ext_vector_type(8))) short bf16x8;

template <int V> using ic = std::integral_constant<int, V>;

static constexpr int B_   = 2048;
static constexpr int IN_  = 1024;
static constexpr int HID_ = 2048;
static constexpr int NB_  = 8;
static constexpr int BS_  = 256;   // block size
static constexpr int G3_  = 768;   // 3*BS_

// packed fp32x2 -> bf16x2 RNE, single VALU op (no builtin on gfx950)
__device__ __forceinline__ unsigned cvtpk(float lo, float hi) {
  unsigned r;
  asm("v_cvt_pk_bf16_f32 %0, %1, %2" : "=v"(r) : "v"(lo), "v"(hi));
  return r;
}

__device__ __forceinline__ unsigned short f2bf(float f) {
  unsigned u = __builtin_bit_cast(unsigned, f);
  u = (u + 0x7FFFu + ((u >> 16) & 1u)) >> 16;
  return (unsigned short)u;
}

// Convert ONLY the weights to bf16 (x and h are converted inside the GEMM's
// A-staging path).
__global__ void cvt_w(const float* __restrict__ Wih, const float* __restrict__ Whh,
                      unsigned short* __restrict__ dst) {
  constexpr int c0 = (NB_ * G3_ * IN_) / 4;
  constexpr int n4 = c0 + (NB_ * G3_ * BS_) / 4;
  int i = blockIdx.x * blockDim.x + threadIdx.x;
  int stride = gridDim.x * blockDim.x;
  for (; i < n4; i += stride) {
    float4 v = (i < c0) ? reinterpret_cast<const float4*>(Wih)[i]
                        : reinterpret_cast<const float4*>(Whh)[i - c0];
    ushort4 o;
    o.x = f2bf(v.x); o.y = f2bf(v.y); o.z = f2bf(v.z); o.w = f2bf(v.w);
    reinterpret_cast<ushort4*>(dst)[i] = o;
  }
}

// ---------- fused block-GRU MFMA kernel: hybrid staging, 2-deep W pipeline ----------
// Tile: 128 batch rows x 64 out-cols (192 gate cols); 4 waves (2x2), wave 64x32.
// Accumulators: [0]=r (K=1280 combined), [1]=z (combined), [2]=i_n, [3]=h_n.
// LDS: 2 buffers x 40KB { A [128][64]bf16 @0, W [192][64]bf16 @16384 },
// XOR-swizzled phys = logical ^ ((row&7)<<4).
// W: global_load_lds from bf16 ws, staged for tile t+2 at the tail of step t
// (round-4 schedule): its 6 DMAs stay in flight across the ENTIRE next step;
// head wait is vmcnt(6), never a fresh drain. A: fp32 loads issued at step head,
// cvt_pk + ds_write at tail after a vmcnt(0) that only drains step-old loads.
// Raw s_barrier throughout (no __syncthreads vmcnt(0) auto-drain); all waits
// clobber-free asm + sched_barrier(0) fences; fully unrolled (compile-time tt).
__global__ __launch_bounds__(256, 2) void gru_mfma(
    const float* __restrict__ xf,              // [2048][1024] fp32
    const float* __restrict__ hf,              // [2048][2048] fp32
    const unsigned short* __restrict__ wihb,   // [8][768][1024] bf16
    const unsigned short* __restrict__ whhb,   // [8][768][256] bf16
    const float* __restrict__ b_ih,            // [8][768]
    const float* __restrict__ b_hh,            // [8][768]
    float* __restrict__ out)                   // [2048][2048]
{
  __shared__ __align__(16) char lds[2][40960];   // per buf: A @0 (16KB), W @16384 (24KB)

  const int t    = threadIdx.x;
  const int lane = t & 63;
  const int wid  = t >> 6;
  const int wm   = wid >> 1;     // wave row (0..1) -> 64-row half
  const int wn   = wid & 1;      // wave col (0..1) -> 32-col half

  // Bijective XCD swizzle: nwg=512 = 8 XCDs x 64 -> each XCD owns one GRU block n
  // (its bf16 W panel = 1.9 MB, L2-resident per XCD).
  const int bid = blockIdx.x;
  const int swz = (bid & 7) * 64 + (bid >> 3);
  const int mrow0 = (swz & 15) * 128;
  const int ct    = swz >> 4;
  const int n     = ct >> 2;          // GRU block index
  const int s0    = (ct & 3) * 64;    // col offset within block

  // Staging pass p targets phys LDS offset op = p*4096 + t*16 (region-local);
  // element there is logical ol = op ^ (((op>>7)&7)<<4) (involution on bits [6:4]).
  int arow[4], acolE[4];
#pragma unroll
  for (int p = 0; p < 4; ++p) {
    int op = p * 4096 + t * 16;
    int ol = op ^ (((op >> 7) & 7) << 4);
    arow[p]  = ol >> 7;           // 0..127
    acolE[p] = (ol & 127) >> 1;   // element offset (multiple of 8)
  }
  int wgrow[6], wcb[6];
#pragma unroll
  for (int q = 0; q < 6; ++q) {
    int op = q * 4096 + t * 16;
    int ol = op ^ (((op >> 7) & 7) << 4);
    int wr = ol >> 7;             // 0..191
    wgrow[q] = n * G3_ + (wr >> 6) * BS_ + s0 + (wr & 63);  // global W row
    wcb[q]   = ol & 127;          // byte offset within 128B row
  }

  f32x4 acc[4][4][2] = {};   // [set][mi][ni]
  float4 sa[4][2];           // A staging regs (32 VGPR)

  auto issueA = [&](int t2) {            // coalesced fp32 loads, staging layout
#pragma unroll
    for (int p = 0; p < 4; ++p) {
      const float* src = (t2 < 16)
        ? xf + (size_t)(mrow0 + arow[p]) * IN_  + t2 * 64 + acolE[p]
        : hf + (size_t)(mrow0 + arow[p]) * HID_ + n * BS_ + (t2 - 16) * 64 + acolE[p];
      sa[p][0] = *reinterpret_cast<const float4*>(src);
      sa[p][1] = *reinterpret_cast<const float4*>(src + 4);
    }
  };
  auto stageW = [&](int buf, int t2) {   // 6x global_load_lds, 16B
    const bool ph1 = t2 < 16;
    const int ks = ph1 ? t2 : (t2 - 16);
    char* base = (char*)lds[buf] + 16384;
#pragma unroll
    for (int q = 0; q < 6; ++q) {
      const char* src = ph1
        ? (const char*)wihb + ((size_t)wgrow[q] * IN_ + ks * 64) * 2 + wcb[q]
        : (const char*)whhb + ((size_t)wgrow[q] * BS_ + ks * 64) * 2 + wcb[q];
      __builtin_amdgcn_global_load_lds((const AS1 void*)src,
                                       (AS3 void*)(base + q * 4096 + wid * 1024), 16, 0, 0);
    }
  };
  auto pack8 = [&](const float4& a, const float4& b) {
    union { unsigned u[4]; bf16x8 v; } r;
    r.u[0] = cvtpk(a.x, a.y); r.u[1] = cvtpk(a.z, a.w);
    r.u[2] = cvtpk(b.x, b.y); r.u[3] = cvtpk(b.z, b.w);
    return r.v;
  };
  auto writeA = [&](int buf) {           // cvt + ds_write (linear phys offset)
    char* base = (char*)lds[buf];
#pragma unroll
    for (int p = 0; p < 4; ++p)
      *reinterpret_cast<bf16x8*>(base + p * 4096 + t * 16) = pack8(sa[p][0], sa[p][1]);
  };

  auto loadA = [&](const char* buf, bf16x8 (&af)[2][4]) {
#pragma unroll
    for (int ksub = 0; ksub < 2; ++ksub)
#pragma unroll
      for (int mi = 0; mi < 4; ++mi) {
        int ar  = wm * 64 + mi * 16 + (lane & 15);
        int off = ar * 128 + ksub * 64 + ((lane >> 4) * 16);
        off ^= (ar & 7) << 4;
        af[ksub][mi] = *reinterpret_cast<const bf16x8*>(buf + off);
      }
  };
  auto loadW = [&](const char* buf, int g, bf16x8 (&wf)[2][2]) {
#pragma unroll
    for (int ksub = 0; ksub < 2; ++ksub)
#pragma unroll
      for (int ni = 0; ni < 2; ++ni) {
        int wr  = g * 64 + wn * 32 + ni * 16 + (lane & 15);
        int off = wr * 128 + ksub * 64 + ((lane >> 4) * 16);
        off ^= (wr & 7) << 4;
        wf[ksub][ni] = *reinterpret_cast<const bf16x8*>(buf + 16384 + off);
      }
  };
  auto mfmaSet = [&](auto setc, bf16x8 (&af)[2][4], bf16x8 (&wf)[2][2]) {
    constexpr int set = decltype(setc)::value;
    __builtin_amdgcn_s_setprio(1);
#pragma unroll
    for (int ksub = 0; ksub < 2; ++ksub)
#pragma unroll
      for (int mi = 0; mi < 4; ++mi)
#pragma unroll
        for (int ni = 0; ni < 2; ++ni)
          acc[set][mi][ni] = __builtin_amdgcn_mfma_f32_16x16x32_bf16(
              af[ksub][mi], wf[ksub][ni], acc[set][mi][ni], 0, 0, 0);
    __builtin_amdgcn_s_setprio(0);
  };

  // ---- prologue: tiles 0 and 1 (A via regs, W via DMA; W1 left in flight) ----
  issueA(0);
  stageW(0, 0);
  asm volatile("s_waitcnt vmcnt(6)");    // A0 done (A0 older than W0)
  __builtin_amdgcn_sched_barrier(0);
  writeA(0);
  issueA(1);
  stageW(1, 1);
  asm volatile("s_waitcnt vmcnt(6)");    // drains W0 + A1; W1's 6 stay in flight
  __builtin_amdgcn_sched_barrier(0);
  writeA(1);
  asm volatile("s_waitcnt lgkmcnt(0)");  // my ds_writes flushed
  __builtin_amdgcn_sched_barrier(0);
  __builtin_amdgcn_s_barrier();          // barrier A for step 0 (W0, A0 visible)

  // ---- 20 K-steps (16 input + 4 hidden), fully unrolled, raw barriers ----
#pragma unroll
  for (int tt = 0; tt < 20; ++tt) {
    const char* cur = (const char*)lds[tt & 1];
    bf16x8 af[2][4], wf[2][2];

    if (tt + 2 < 20) issueA(tt + 2);        // head issue: ages a full compute
    __builtin_amdgcn_sched_barrier(0);

    loadA(cur, af);
    loadW(cur, 0, wf); mfmaSet(ic<0>{}, af, wf);
    loadW(cur, 1, wf); mfmaSet(ic<1>{}, af, wf);
    loadW(cur, 2, wf);
    if (tt < 16) mfmaSet(ic<2>{}, af, wf);
    else         mfmaSet(ic<3>{}, af, wf);

    asm volatile("s_waitcnt lgkmcnt(0)");   // my ds_reads of cur retired
    __builtin_amdgcn_sched_barrier(0);
    __builtin_amdgcn_s_barrier();           // barrier B: cur released by all waves

    if (tt + 2 < 20) {
      asm volatile("s_waitcnt vmcnt(0)");   // A(tt+2) landed; W(tt+1) is step-old
      __builtin_amdgcn_sched_barrier(0);
      writeA(tt & 1);                       // tile tt+2 A into freed cur
      stageW(tt & 1, tt + 2);               // 6 DMAs: in flight across next step
      asm volatile("s_waitcnt lgkmcnt(0)"); // A ds_writes flushed
      __builtin_amdgcn_sched_barrier(0);
    }
    if (tt < 19) {
      if (tt + 2 < 20) asm volatile("s_waitcnt vmcnt(6)");  // W(tt+1) landed
      else             asm volatile("s_waitcnt vmcnt(0)");  // tail: W(19) landed
      __builtin_amdgcn_sched_barrier(0);
      __builtin_amdgcn_s_barrier();         // barrier A for step tt+1
    }
  }

  // ---- epilogue: gates + output ----
#pragma unroll
  for (int ni = 0; ni < 2; ++ni) {
    int scol = s0 + wn * 32 + ni * 16 + (lane & 15);
    float br_i = b_ih[n * G3_ + 0 * BS_ + scol];
    float bz_i = b_ih[n * G3_ + 1 * BS_ + scol];
    float bn_i = b_ih[n * G3_ + 2 * BS_ + scol];
    float br_h = b_hh[n * G3_ + 0 * BS_ + scol];
    float bz_h = b_hh[n * G3_ + 1 * BS_ + scol];
    float bn_h = b_hh[n * G3_ + 2 * BS_ + scol];
    int gcol = n * BS_ + scol;
#pragma unroll
    for (int mi = 0; mi < 4; ++mi) {
#pragma unroll
      for (int i = 0; i < 4; ++i) {
        int row = mrow0 + wm * 64 + mi * 16 + (lane >> 4) * 4 + i;  // C/D: col=lane&15, row=(lane>>4)*4+reg
        float hprev = hf[(size_t)row * HID_ + gcol];
        float rr = acc[0][mi][ni][i] + br_i + br_h;
        float zz = acc[1][mi][ni][i] + bz_i + bz_h;
        float r  = 1.f / (1.f + __expf(-rr));
        float z  = 1.f / (1.f + __expf(-zz));
        float ng = tanhf(acc[2][mi][ni][i] + bn_i + r * (acc[3][mi][ni][i] + bn_h));
        out[(size_t)row * HID_ + gcol] = (1.f - z) * ng + z * hprev;
      }
    }
  }
}

// ---------- fallback (only if ws too small): naive fp32 ----------
__global__ void gru_naive(const float* __restrict__ x, const float* __restrict__ h,
                          const float* __restrict__ Wih, const float* __restrict__ Whh,
                          const float* __restrict__ bih, const float* __restrict__ bhh,
                          float* __restrict__ out) {
  int b = blockIdx.x;
  int n = blockIdx.y;
  int s = threadIdx.x;   // 256
  __shared__ float xs[1024];
  __shared__ float hs[256];
  for (int i = threadIdx.x; i < 1024; i += 256) xs[i] = x[(size_t)b * IN_ + i];
  if (threadIdx.x < 256) hs[threadIdx.x] = h[(size_t)b * HID_ + n * BS_ + threadIdx.x];
  __syncthreads();
  float gi[3], gh[3];
  for (int g = 0; g < 3; ++g) {
    const float* w = Wih + ((size_t)(n * G3_ + g * BS_ + s)) * IN_;
    float a = 0.f;
    for (int k = 0; k < IN_; ++k) a += xs[k] * w[k];
    gi[g] = a + bih[n * G3_ + g * BS_ + s];
    const float* w2 = Whh + ((size_t)(n * G3_ + g * BS_ + s)) * BS_;
    float a2 = 0.f;
    for (int k = 0; k < BS_; ++k) a2 += hs[k] * w2[k];
    gh[g] = a2 + bhh[n * G3_ + g * BS_ + s];
  }
  float r = 1.f / (1.f + expf(-(gi[0] + gh[0])));
  float z = 1.f / (1.f + expf(-(gi[1] + gh[1])));
  float ng = tanhf(gi[2] + r * gh[2]);
  out[(size_t)b * HID_ + n * BS_ + s] = (1.f - z) * ng + z * hs[s];
}

extern "C" void kernel_launch(void* const* d_in, const int* in_sizes, int n_in,
                              void* d_out, int out_size, void* d_ws, size_t ws_size,
                              hipStream_t stream) {
  const float* x   = (const float*)d_in[0];
  const float* h   = (const float*)d_in[1];
  const float* Wih = (const float*)d_in[2];
  const float* Whh = (const float*)d_in[3];
  const float* bih = (const float*)d_in[4];
  const float* bhh = (const float*)d_in[5];
  float* out = (float*)d_out;

  const size_t szwih = (size_t)NB_ * G3_ * IN_;
  const size_t szwhh = (size_t)NB_ * G3_ * BS_;
  const size_t need  = (szwih + szwhh) * 2;

  if (ws_size >= need) {
    unsigned short* wihb = (unsigned short*)d_ws;
    unsigned short* whhb = wihb + szwih;
    cvt_w<<<1024, 256, 0, stream>>>(Wih, Whh, wihb);
    gru_mfma<<<512, 256, 0, stream>>>(x, h, wihb, whhb, bih, bhh, out);
  } else {
    dim3 grid(B_, NB_);
    gru_naive<<<grid, 256, 0, stream>>>(x, h, Wih, Whh, bih, bhh, out);
  }
}